// Round 3
// baseline (356.514 us; speedup 1.0000x reference)
//
#include <hip/hip_runtime.h>

#define IMG_H 512
#define IMG_W 512
#define NIMG 96            // B*C
#define WOUT 506
#define STRIP 11
#define NSTRIPS 46         // 46*11 = 506
#define NBLK (NSTRIPS*NIMG)   // 4416, divisible by 8
#define TOTAL_VALS 24579456.0f   // 96 * 506 * 506

__device__ __forceinline__ unsigned fkey(float f){
    unsigned b = __float_as_uint(f);
    return (b & 0x80000000u) ? ~b : (b | 0x80000000u);
}
__device__ __forceinline__ float fdec(unsigned k){
    unsigned b = (k & 0x80000000u) ? (k ^ 0x80000000u) : ~k;
    return __uint_as_float(b);
}

// ---------------- kernel 1: per-batch-image min/max of img2 ----------------
// 2048 blocks = 32 images * 64 chunks  ->  32 waves/CU, BW-bound.
__global__ __launch_bounds__(256) void minmax_kernel(const float4* __restrict__ y4,
                                                     unsigned* __restrict__ maxk,
                                                     unsigned* __restrict__ mink){
    int blk  = blockIdx.x;
    int img  = blk >> 6;            // batch index 0..31
    int chnk = blk & 63;
    const float4* base = y4 + (size_t)img * 196608 + (size_t)chnk * 3072;
    float mn = 3.4e38f, mx = -3.4e38f;
    for (int i = threadIdx.x; i < 3072; i += 256){
        float4 v = base[i];
        mn = fminf(mn, fminf(fminf(v.x, v.y), fminf(v.z, v.w)));
        mx = fmaxf(mx, fmaxf(fmaxf(v.x, v.y), fmaxf(v.z, v.w)));
    }
    #pragma unroll
    for (int off = 32; off; off >>= 1){
        mn = fminf(mn, __shfl_down(mn, off));
        mx = fmaxf(mx, __shfl_down(mx, off));
    }
    if ((threadIdx.x & 63) == 0){
        atomicMax(&maxk[img], fkey(mx));
        atomicMin(&mink[img], fkey(mn));
    }
}

// ---------------- kernel 2: SSIM map + accumulate ----------------
// One wave per block. Thread t owns input columns [8t, 8t+8).
// Vertical 7-row sliding sums in registers; horizontal 7-sum via 6 shuffles
// from thread t+1 (no LDS, no barriers).

#define ROWOP(row, OPA) { \
    const float* xr = x + (size_t)(row)*IMG_W + c0; \
    const float* yr = y + (size_t)(row)*IMG_W + c0; \
    float4 xa = *(const float4*)xr;     float4 xb = *(const float4*)(xr+4); \
    float4 ya = *(const float4*)yr;     float4 yb = *(const float4*)(yr+4); \
    float xv[8] = {xa.x,xa.y,xa.z,xa.w,xb.x,xb.y,xb.z,xb.w}; \
    float yv[8] = {ya.x,ya.y,ya.z,ya.w,yb.x,yb.y,yb.z,yb.w}; \
    _Pragma("unroll") \
    for (int k = 0; k < 8; k++){ \
        sx[k]  OPA xv[k]; \
        sy[k]  OPA yv[k]; \
        sxx[k] OPA xv[k]*xv[k]; \
        syy[k] OPA yv[k]*yv[k]; \
        sxy[k] OPA xv[k]*yv[k]; \
    } }

// outw[j] = sum over 7 consecutive column sums starting at col 8t+j.
#define HSHUF(s, outw) { \
    float n0=__shfl_down(s[0],1), n1=__shfl_down(s[1],1), n2=__shfl_down(s[2],1); \
    float n3=__shfl_down(s[3],1), n4=__shfl_down(s[4],1), n5=__shfl_down(s[5],1); \
    float w = s[0]+s[1]+s[2]+s[3]+s[4]+s[5]+s[6]; \
    outw[0]=w; \
    w += s[7]-s[0]; outw[1]=w; \
    w += n0-s[1];   outw[2]=w; \
    w += n1-s[2];   outw[3]=w; \
    w += n2-s[3];   outw[4]=w; \
    w += n3-s[4];   outw[5]=w; \
    w += n4-s[5];   outw[6]=w; \
    w += n5-s[6];   outw[7]=w; }

__global__ __launch_bounds__(64) void ssim_kernel(const float* __restrict__ img1,
                                                  const float* __restrict__ img2,
                                                  const unsigned* __restrict__ maxk,
                                                  const unsigned* __restrict__ mink,
                                                  float* __restrict__ acc){
    // XCD-bijective swizzle (NBLK % 8 == 0): logical index L groups all strips
    // of one image on one XCD -> halo rows are L2 hits.
    int bid = blockIdx.x;
    int L   = (bid & 7) * (NBLK/8) + (bid >> 3);
    int img   = L / NSTRIPS;
    int strip = L - img * NSTRIPS;
    int b     = img / 3;

    float dr = fdec(maxk[b]) - fdec(mink[b]);
    float c1 = 0.01f * dr;  c1 *= c1;
    float c2 = 0.03f * dr;  c2 *= c2;
    // scaled constants: work with raw 7x7 sums (no /49), scale by 2401 = 49^2
    const float c1s = 2401.0f * c1;
    const float c2s = 2401.0f * c2;
    const float CO2 = 2.0f * 49.0f / 48.0f;   // 2*covn
    const float COV = 49.0f / 48.0f;          // covn

    const float* x = img1 + (size_t)img * (IMG_H*IMG_W);
    const float* y = img2 + (size_t)img * (IMG_H*IMG_W);

    int t  = threadIdx.x;
    int c0 = t * 8;

    float sx[8]={0,0,0,0,0,0,0,0}, sy[8]={0,0,0,0,0,0,0,0};
    float sxx[8]={0,0,0,0,0,0,0,0}, syy[8]={0,0,0,0,0,0,0,0}, sxy[8]={0,0,0,0,0,0,0,0};

    int r0 = strip * STRIP;

    for (int rr = 0; rr < 7; rr++){ ROWOP(r0+rr, +=) }

    float accS = 0.0f;

    for (int r = r0; r < r0 + STRIP; r++){
        float wsx[8], wsy[8], wsxx[8], wsyy[8], wsxy[8];
        HSHUF(sx, wsx)  HSHUF(sy, wsy)  HSHUF(sxx, wsxx)
        HSHUF(syy, wsyy)  HSHUF(sxy, wsxy)

        #pragma unroll
        for (int j = 0; j < 8; j++){
            if (c0 + j < WOUT){
                float P = wsx[j], Q = wsy[j];
                float t1 = P*Q;
                float t2 = fmaf(P, P, Q*Q);
                float a1 = fmaf(2.0f, t1, c1s);              // 2PQ + 2401*C1
                float b1 = t2 + c1s;                          // P^2+Q^2 + 2401*C1
                float u  = fmaf(49.0f, wsxy[j], -t1);         // 49R - PQ
                float a2 = fmaf(CO2, u, c2s);                 // 2*covn*u + 2401*C2
                float v  = fmaf(49.0f, wsxx[j]+wsyy[j], -t2); // 49(XX+YY) - (P^2+Q^2)
                float b2 = fmaf(COV, v, c2s);
                accS += (a1*a2) * __builtin_amdgcn_rcpf(b1*b2);
            }
        }

        if (r < r0 + STRIP - 1){
            ROWOP(r+7, +=)   // entering row
            ROWOP(r,   -=)   // leaving row (L1/L2-resident reload)
        }
    }

    #pragma unroll
    for (int off = 32; off; off >>= 1)
        accS += __shfl_down(accS, off);
    if (t == 0)
        atomicAdd(acc, accS);
}

// ---------------- kernel 3: finalize ----------------
__global__ void finalize_kernel(const float* __restrict__ acc, float* __restrict__ out){
    out[0] = 1.0f - acc[0] * (1.0f / TOTAL_VALS);
}

extern "C" void kernel_launch(void* const* d_in, const int* in_sizes, int n_in,
                              void* d_out, int out_size, void* d_ws, size_t ws_size,
                              hipStream_t stream) {
    const float* img1 = (const float*)d_in[0];
    const float* img2 = (const float*)d_in[1];
    float* out = (float*)d_out;

    char* ws = (char*)d_ws;
    float*    acc  = (float*)ws;              // offset 0
    unsigned* maxk = (unsigned*)(ws + 128);   // 32 uints
    unsigned* mink = (unsigned*)(ws + 256);   // 32 uints

    hipMemsetAsync(ws, 0, 256, stream);          // acc = 0, maxk = 0
    hipMemsetAsync(ws + 256, 0xFF, 128, stream); // mink = 0xFFFFFFFF

    minmax_kernel<<<2048, 256, 0, stream>>>((const float4*)img2, maxk, mink);
    ssim_kernel<<<NBLK, 64, 0, stream>>>(img1, img2, maxk, mink, acc);
    finalize_kernel<<<1, 1, 0, stream>>>(acc, out);
}

// Round 4
// 287.525 us; speedup vs baseline: 1.2399x; 1.2399x over previous
//
#include <hip/hip_runtime.h>

#define IMG_H 512
#define IMG_W 512
#define NIMG 96            // B*C
#define WOUT 506
#define STRIP 11
#define NSTRIPS 46         // 46*11 = 506
#define NBLK (NSTRIPS*NIMG)   // 4416, divisible by 8
#define TOTAL_VALS 24579456.0f   // 96 * 506 * 506

// ws layout (floats): pmn[NBLK] @0, pmx[NBLK] @8192, pss[NBLK] @16384
#define WS_MN 0
#define WS_MX 8192
#define WS_SS 16384
#define WS_NEED ((WS_SS + NBLK) * 4)

__device__ __forceinline__ int swz(int bid){           // XCD-bijective (NBLK%8==0)
    return (bid & 7) * (NBLK / 8) + (bid >> 3);
}

// ---------------- kernel 1: per-(img,strip) min/max partials of img2 -------
// Reads exactly the y-rows its k2 twin will read -> warms L3 (img2 fits L3).
__global__ __launch_bounds__(64) void minmax_part(const float* __restrict__ img2,
                                                  float* __restrict__ ws){
    int L     = swz(blockIdx.x);
    int img   = L / NSTRIPS;
    int strip = L - img * NSTRIPS;
    int r0    = strip * STRIP;                // rows [r0, r0+17), always <=512

    const float4* y4 = (const float4*)(img2 + (size_t)img * (IMG_H*IMG_W)) + r0 * 128;
    float mn = 3.4e38f, mx = -3.4e38f;
    #pragma unroll 4
    for (int i = threadIdx.x; i < 17*128; i += 64){
        float4 v = y4[i];
        mn = fminf(mn, fminf(fminf(v.x, v.y), fminf(v.z, v.w)));
        mx = fmaxf(mx, fmaxf(fmaxf(v.x, v.y), fmaxf(v.z, v.w)));
    }
    #pragma unroll
    for (int off = 32; off; off >>= 1){
        mn = fminf(mn, __shfl_down(mn, off));
        mx = fmaxf(mx, __shfl_down(mx, off));
    }
    if (threadIdx.x == 0){
        ws[WS_MN + L] = mn;
        ws[WS_MX + L] = mx;
    }
}

// ---------------- kernel 2: SSIM map + per-block partial ----------------
// One wave per block. Thread t owns input columns [8t, 8t+8).
// Vertical 7-row sliding sums in registers; horizontal 7-sum via 6 shuffles.
// Row loads for the NEXT slide are issued before the window math (prefetch).

#define ROWOP(row, OPA) { \
    const float* xr = x + (size_t)(row)*IMG_W + c0; \
    const float* yr = y + (size_t)(row)*IMG_W + c0; \
    float4 xa = *(const float4*)xr;     float4 xb = *(const float4*)(xr+4); \
    float4 ya = *(const float4*)yr;     float4 yb = *(const float4*)(yr+4); \
    float xv[8] = {xa.x,xa.y,xa.z,xa.w,xb.x,xb.y,xb.z,xb.w}; \
    float yv[8] = {ya.x,ya.y,ya.z,ya.w,yb.x,yb.y,yb.z,yb.w}; \
    _Pragma("unroll") \
    for (int k = 0; k < 8; k++){ \
        sx[k]  OPA xv[k]; \
        sy[k]  OPA yv[k]; \
        sxx[k] OPA xv[k]*xv[k]; \
        syy[k] OPA yv[k]*yv[k]; \
        sxy[k] OPA xv[k]*yv[k]; \
    } }

#define HSHUF(s, outw) { \
    float n0=__shfl_down(s[0],1), n1=__shfl_down(s[1],1), n2=__shfl_down(s[2],1); \
    float n3=__shfl_down(s[3],1), n4=__shfl_down(s[4],1), n5=__shfl_down(s[5],1); \
    float w = s[0]+s[1]+s[2]+s[3]+s[4]+s[5]+s[6]; \
    outw[0]=w; \
    w += s[7]-s[0]; outw[1]=w; \
    w += n0-s[1];   outw[2]=w; \
    w += n1-s[2];   outw[3]=w; \
    w += n2-s[3];   outw[4]=w; \
    w += n3-s[4];   outw[5]=w; \
    w += n4-s[5];   outw[6]=w; \
    w += n5-s[6];   outw[7]=w; }

template<int USE_WS>
__global__ __launch_bounds__(64) void ssim_kernel(const float* __restrict__ img1,
                                                  const float* __restrict__ img2,
                                                  float* __restrict__ ws,
                                                  float* __restrict__ acc){
    int L     = swz(blockIdx.x);
    int img   = L / NSTRIPS;
    int strip = L - img * NSTRIPS;
    int b     = img / 3;

    // data range of batch b: reduce 138 contiguous partials (uniform -> scalar)
    float mn = 3.4e38f, mx = -3.4e38f;
    if (USE_WS){
        const float* pmn = ws + WS_MN + b * 3 * NSTRIPS;
        const float* pmx = ws + WS_MX + b * 3 * NSTRIPS;
        #pragma unroll 6
        for (int i = 0; i < 3*NSTRIPS; i++){
            mn = fminf(mn, pmn[i]);
            mx = fmaxf(mx, pmx[i]);
        }
    } else {
        // fallback: ws[0..31]=maxkey, ws[32..63]=minkey (order-preserving uint)
        unsigned mk = ((const unsigned*)ws)[b];
        unsigned nk = ((const unsigned*)ws)[32 + b];
        unsigned mb = (mk & 0x80000000u) ? (mk ^ 0x80000000u) : ~mk;
        unsigned nb = (nk & 0x80000000u) ? (nk ^ 0x80000000u) : ~nk;
        mx = __uint_as_float(mb); mn = __uint_as_float(nb);
    }
    float dr = mx - mn;
    float c1 = 0.01f * dr;  c1 *= c1;
    float c2 = 0.03f * dr;  c2 *= c2;
    const float c1s = 2401.0f * c1;           // work with raw 7x7 sums
    const float c2s = 2401.0f * c2;
    const float CO2 = 2.0f * 49.0f / 48.0f;
    const float COV = 49.0f / 48.0f;

    const float* x = img1 + (size_t)img * (IMG_H*IMG_W);
    const float* y = img2 + (size_t)img * (IMG_H*IMG_W);

    int t  = threadIdx.x;
    int c0 = t * 8;

    float sx[8]={0,0,0,0,0,0,0,0}, sy[8]={0,0,0,0,0,0,0,0};
    float sxx[8]={0,0,0,0,0,0,0,0}, syy[8]={0,0,0,0,0,0,0,0}, sxy[8]={0,0,0,0,0,0,0,0};

    int r0 = strip * STRIP;

    #pragma unroll
    for (int rr = 0; rr < 7; rr++){ ROWOP(r0+rr, +=) }

    float accS = 0.0f;

    for (int r = r0; r < r0 + STRIP; r++){
        bool more = (r < r0 + STRIP - 1);
        // ---- prefetch next slide's rows into registers (issued before math)
        float4 EX0,EX1,EY0,EY1, LX0,LX1,LY0,LY1;
        if (more){
            const float* xe = x + (size_t)(r+7)*IMG_W + c0;
            const float* ye = y + (size_t)(r+7)*IMG_W + c0;
            const float* xl = x + (size_t)r*IMG_W + c0;
            const float* yl = y + (size_t)r*IMG_W + c0;
            EX0 = *(const float4*)xe;  EX1 = *(const float4*)(xe+4);
            EY0 = *(const float4*)ye;  EY1 = *(const float4*)(ye+4);
            LX0 = *(const float4*)xl;  LX1 = *(const float4*)(xl+4);
            LY0 = *(const float4*)yl;  LY1 = *(const float4*)(yl+4);
        }

        float wsx[8], wsy[8], wsxx[8], wsyy[8], wsxy[8];
        HSHUF(sx, wsx)  HSHUF(sy, wsy)  HSHUF(sxx, wsxx)
        HSHUF(syy, wsyy)  HSHUF(sxy, wsxy)

        #pragma unroll
        for (int j = 0; j < 8; j++){
            if (c0 + j < WOUT){
                float P = wsx[j], Q = wsy[j];
                float t1 = P*Q;
                float t2 = fmaf(P, P, Q*Q);
                float a1 = fmaf(2.0f, t1, c1s);
                float b1 = t2 + c1s;
                float u  = fmaf(49.0f, wsxy[j], -t1);
                float a2 = fmaf(CO2, u, c2s);
                float v  = fmaf(49.0f, wsxx[j]+wsyy[j], -t2);
                float b2 = fmaf(COV, v, c2s);
                accS += (a1*a2) * __builtin_amdgcn_rcpf(b1*b2);
            }
        }

        if (more){
            float xv[8] = {EX0.x,EX0.y,EX0.z,EX0.w,EX1.x,EX1.y,EX1.z,EX1.w};
            float yv[8] = {EY0.x,EY0.y,EY0.z,EY0.w,EY1.x,EY1.y,EY1.z,EY1.w};
            float lx[8] = {LX0.x,LX0.y,LX0.z,LX0.w,LX1.x,LX1.y,LX1.z,LX1.w};
            float ly[8] = {LY0.x,LY0.y,LY0.z,LY0.w,LY1.x,LY1.y,LY1.z,LY1.w};
            #pragma unroll
            for (int k = 0; k < 8; k++){
                sx[k]  += xv[k] - lx[k];
                sy[k]  += yv[k] - ly[k];
                sxx[k] += xv[k]*xv[k] - lx[k]*lx[k];
                syy[k] += yv[k]*yv[k] - ly[k]*ly[k];
                sxy[k] += xv[k]*yv[k] - lx[k]*ly[k];
            }
        }
    }

    #pragma unroll
    for (int off = 32; off; off >>= 1)
        accS += __shfl_down(accS, off);
    if (t == 0){
        if (USE_WS) ws[WS_SS + L] = accS;
        else        atomicAdd(acc, accS);
    }
}

// ---------------- kernel 3: reduce partials + finalize ----------------
__global__ __launch_bounds__(64) void finalize_ws(const float* __restrict__ ws,
                                                  float* __restrict__ out){
    float s = 0.0f;
    for (int i = threadIdx.x; i < NBLK; i += 64) s += ws[WS_SS + i];
    #pragma unroll
    for (int off = 32; off; off >>= 1) s += __shfl_down(s, off);
    if (threadIdx.x == 0) out[0] = 1.0f - s * (1.0f / TOTAL_VALS);
}

__global__ void finalize_acc(const float* __restrict__ acc, float* __restrict__ out){
    out[0] = 1.0f - acc[0] * (1.0f / TOTAL_VALS);
}

// ---------------- fallback minmax (atomic, needs memset init) ----------------
__device__ __forceinline__ unsigned fkey(float f){
    unsigned b = __float_as_uint(f);
    return (b & 0x80000000u) ? ~b : (b | 0x80000000u);
}
__global__ __launch_bounds__(256) void minmax_atomic(const float4* __restrict__ y4,
                                                     unsigned* __restrict__ ws){
    int blk  = blockIdx.x;
    int img  = blk >> 6;
    int chnk = blk & 63;
    const float4* base = y4 + (size_t)img * 196608 + (size_t)chnk * 3072;
    float mn = 3.4e38f, mx = -3.4e38f;
    for (int i = threadIdx.x; i < 3072; i += 256){
        float4 v = base[i];
        mn = fminf(mn, fminf(fminf(v.x, v.y), fminf(v.z, v.w)));
        mx = fmaxf(mx, fmaxf(fmaxf(v.x, v.y), fmaxf(v.z, v.w)));
    }
    #pragma unroll
    for (int off = 32; off; off >>= 1){
        mn = fminf(mn, __shfl_down(mn, off));
        mx = fmaxf(mx, __shfl_down(mx, off));
    }
    if ((threadIdx.x & 63) == 0){
        atomicMax(&ws[img], fkey(mx));
        atomicMin(&ws[32 + img], fkey(mn));
    }
}

extern "C" void kernel_launch(void* const* d_in, const int* in_sizes, int n_in,
                              void* d_out, int out_size, void* d_ws, size_t ws_size,
                              hipStream_t stream) {
    const float* img1 = (const float*)d_in[0];
    const float* img2 = (const float*)d_in[1];
    float* out = (float*)d_out;
    float* ws  = (float*)d_ws;

    if (ws_size >= WS_NEED){
        // atomic-free, memset-free 3-kernel pipeline
        minmax_part<<<NBLK, 64, 0, stream>>>(img2, ws);
        ssim_kernel<1><<<NBLK, 64, 0, stream>>>(img1, img2, ws, nullptr);
        finalize_ws<<<1, 64, 0, stream>>>(ws, out);
    } else {
        // fallback: small-ws atomic path
        hipMemsetAsync(ws, 0, 160, stream);             // maxkeys=0
        hipMemsetAsync((char*)ws + 128, 0xFF, 128, stream); // minkeys=0xFF.. (ws[32..63])
        hipMemsetAsync((char*)ws + 256, 0, 16, stream);     // acc
        float* acc = ws + 64;
        minmax_atomic<<<2048, 256, 0, stream>>>((const float4*)img2, (unsigned*)ws);
        ssim_kernel<0><<<NBLK, 64, 0, stream>>>(img1, img2, ws, acc);
        finalize_acc<<<1, 1, 0, stream>>>(acc, out);
    }
}